// Round 3
// baseline (431.334 us; speedup 1.0000x reference)
//
#include <hip/hip_runtime.h>

#define THRESH 0.05f

typedef __attribute__((ext_vector_type(4)))  int   int32x4;
typedef __attribute__((ext_vector_type(16))) int   int32x16;
typedef __attribute__((ext_vector_type(4)))  float floatx4;

// ---------------------------------------------------------------------------
// Kernel 1: quantize weight [1024,1024] fp32 -> int8 {-1,0,+1} in FRAGMENT
// ORDER for the mfma_i32_32x32x32_i8 B-operand:
//   1 KB block per (nb,k):  wqf[((nb*32 + k)*64 + lane)*16 + byte]
//   lane l supplies w[col = nb*32 + (l&31)][k*32 + (l>>5)*16 .. +16)
// so a wave's B-fragment load is one 1 KB lane-contiguous dwordx4 burst.
// (unchanged -- verified absmax 0 in rounds 0/1.)
// ---------------------------------------------------------------------------
__global__ __launch_bounds__(256) void quant_w_kernel(const float* __restrict__ w,
                                                      signed char* __restrict__ wqf) {
    int c = blockIdx.x * 256 + threadIdx.x;   // 16-byte chunk id, 0..65535
    int l  = c & 63;
    int k  = (c >> 6) & 31;
    int nb = c >> 11;
    int col   = nb * 32 + (l & 31);
    int kbase = k * 32 + (l >> 5) * 16;
    const float* src = w + col * 1024 + kbase;
    signed char q[16];
    #pragma unroll
    for (int j = 0; j < 4; ++j) {
        float4 f = *(const float4*)(src + j * 4);
        q[j * 4 + 0] = (signed char)((f.x >= THRESH) - (f.x <= -THRESH));
        q[j * 4 + 1] = (signed char)((f.y >= THRESH) - (f.y <= -THRESH));
        q[j * 4 + 2] = (signed char)((f.z >= THRESH) - (f.z <= -THRESH));
        q[j * 4 + 3] = (signed char)((f.w >= THRESH) - (f.w <= -THRESH));
    }
    *(int32x4*)(wqf + (size_t)c * 16) = *(const int32x4*)q;
}

// ---------------------------------------------------------------------------
// Kernel 2: 64-row slab ternary GEMM, 32x32x32 i8 MFMA.
// Block = 512 threads (8 waves) x 64-row slab x all 1024 cols; 64 KB LDS,
// grid 512 -> 2 blocks/CU, 16 waves/CU.
// vs round 1 (105 us, all pipes <13% busy -> latency-bound):
//  * 64-row slab halves wqf L2 traffic (1 GB -> 512 MB, ~75K -> ~37K cyc/CU)
//    and doubles MACs per B byte. MFMA count unchanged.
//  * B software-pipelined: distance-4 rolling prefetch, NO sched_barrier.
//    Round 1 serialized 32 L2 round-trips per wave behind a full
//    sched_barrier(0); that was the dominant stall.
//  * A-slab stored in FRAGMENT ORDER with lane-XOR swizzle: both phase-1
//    ds_write and k-loop ds_read_b128 are bijective permutations of a
//    contiguous 1 KB per wave -> zero bank conflicts (was 2.1M cyc).
//    LDS block (k,ri) at (k*2+ri)*1024; slot = lane ^ (k&7).
// ---------------------------------------------------------------------------
__global__ __launch_bounds__(512, 4) void tern_gemm_kernel(const float* __restrict__ x,
                                                           const signed char* __restrict__ wqf,
                                                           float* __restrict__ out) {
    __shared__ __attribute__((aligned(16))) signed char a_lds[64 * 1024];
    const int tid = threadIdx.x;
    const long rowbase = (long)blockIdx.x * 64;

    // ---- Phase 1: stage + quantize x slab (64 rows x 1024 K) into
    //      fragment-order LDS. chunk c: row = c>>6, cir = c&63.
    //      k = cir>>1, hi = cir&1, ri = row>>5 ->
    //      lds addr = (k*2+ri)*1024 + ((hi*32 + (row&31)) ^ (k&7))*16
    //      Global reads stay fully coalesced (4 KB/wave/instr); writes spread
    //      uniformly over all 8 bank groups (k&7 cycles with cir = lane).
    #pragma unroll
    for (int i = 0; i < 8; ++i) {
        int c   = tid + i * 512;   // chunk id 0..4095
        int row = c >> 6;          // 64 chunks per row
        int cir = c & 63;          // chunk-in-row
        const floatx4* src = (const floatx4*)(x + (rowbase + row) * 1024 + cir * 16);
        signed char q[16];
        #pragma unroll
        for (int j = 0; j < 4; ++j) {
            floatx4 f = __builtin_nontemporal_load(src + j);
            #pragma unroll
            for (int e = 0; e < 4; ++e)
                q[j * 4 + e] = (signed char)((f[e] >= THRESH) - (f[e] <= -THRESH));
        }
        int k    = cir >> 1;
        int blk  = k * 2 + (row >> 5);
        int slot = ((cir & 1) * 32 + (row & 31)) ^ (k & 7);
        *(int32x4*)(a_lds + blk * 1024 + slot * 16) = *(const int32x4*)q;
    }
    __syncthreads();

    // ---- Phase 2: compute ----
    const int wave = tid >> 6;    // 0..7
    const int lane = tid & 63;
    const int l31  = lane & 31;
    const int hi   = lane >> 5;

    for (int ot = 0; ot < 2; ++ot) {
        // wave owns 64 cols = two adjacent 32-col B tiles
        const int nb0 = ot * 16 + wave * 2;
        const signed char* bp0 = wqf + (size_t)nb0 * 32768 + lane * 16;
        const signed char* bp1 = bp0 + 32768;

        int32x16 acc00 = {0,0,0,0,0,0,0,0,0,0,0,0,0,0,0,0};  // ri=0, nt=0
        int32x16 acc01 = acc00;                               // ri=0, nt=1
        int32x16 acc10 = acc00;                               // ri=1, nt=0
        int32x16 acc11 = acc00;                               // ri=1, nt=1

        // distance-4 rolling B prefetch (static indices only; rule #20)
        int32x4 b0[4], b1[4];
        #pragma unroll
        for (int j = 0; j < 4; ++j) {
            b0[j] = *(const int32x4*)(bp0 + (size_t)j * 1024);
            b1[j] = *(const int32x4*)(bp1 + (size_t)j * 1024);
        }

        for (int kk = 0; kk < 28; kk += 4) {
            #pragma unroll
            for (int j = 0; j < 4; ++j) {
                const int k  = kk + j;
                const int sl = ((lane ^ (k & 7)) * 16);
                int32x4 af0 = *(const int32x4*)(a_lds + (k * 2 + 0) * 1024 + sl);
                int32x4 af1 = *(const int32x4*)(a_lds + (k * 2 + 1) * 1024 + sl);
                acc00 = __builtin_amdgcn_mfma_i32_32x32x32_i8(af0, b0[j], acc00, 0, 0, 0);
                acc01 = __builtin_amdgcn_mfma_i32_32x32x32_i8(af0, b1[j], acc01, 0, 0, 0);
                acc10 = __builtin_amdgcn_mfma_i32_32x32x32_i8(af1, b0[j], acc10, 0, 0, 0);
                acc11 = __builtin_amdgcn_mfma_i32_32x32x32_i8(af1, b1[j], acc11, 0, 0, 0);
                // refill this slot with k+4 (compiler renames; loads float up)
                b0[j] = *(const int32x4*)(bp0 + (size_t)(k + 4) * 1024);
                b1[j] = *(const int32x4*)(bp1 + (size_t)(k + 4) * 1024);
            }
        }
        // tail k = 28..31, no prefetch
        #pragma unroll
        for (int j = 0; j < 4; ++j) {
            const int k  = 28 + j;
            const int sl = ((lane ^ (k & 7)) * 16);
            int32x4 af0 = *(const int32x4*)(a_lds + (k * 2 + 0) * 1024 + sl);
            int32x4 af1 = *(const int32x4*)(a_lds + (k * 2 + 1) * 1024 + sl);
            acc00 = __builtin_amdgcn_mfma_i32_32x32x32_i8(af0, b0[j], acc00, 0, 0, 0);
            acc01 = __builtin_amdgcn_mfma_i32_32x32x32_i8(af0, b1[j], acc01, 0, 0, 0);
            acc10 = __builtin_amdgcn_mfma_i32_32x32x32_i8(af1, b0[j], acc10, 0, 0, 0);
            acc11 = __builtin_amdgcn_mfma_i32_32x32x32_i8(af1, b1[j], acc11, 0, 0, 0);
        }

        // ---- epilogue: scalar nt stores; per instr 64 lanes cover two
        //      contiguous 128 B row segments ----
        const int cb = nb0 * 32 + l31;
        #pragma unroll
        for (int r = 0; r < 16; ++r) {
            const int rit = (r & 3) + 8 * (r >> 2) + 4 * hi;
            float* o0 = out + (rowbase + rit) * 1024 + cb;        // ri=0 rows
            float* o1 = o0 + 32L * 1024;                          // ri=1 rows
            __builtin_nontemporal_store((float)acc00[r], o0);
            __builtin_nontemporal_store((float)acc01[r], o0 + 32);
            __builtin_nontemporal_store((float)acc10[r], o1);
            __builtin_nontemporal_store((float)acc11[r], o1 + 32);
        }
    }
}

extern "C" void kernel_launch(void* const* d_in, const int* in_sizes, int n_in,
                              void* d_out, int out_size, void* d_ws, size_t ws_size,
                              hipStream_t stream) {
    const float* x = (const float*)d_in[0];      // [32768, 1024] fp32
    const float* w = (const float*)d_in[1];      // [1024, 1024] fp32
    float* out = (float*)d_out;                  // [32768, 1024] fp32
    signed char* wqf = (signed char*)d_ws;       // 1 MB int8 scratch (fragment order)

    quant_w_kernel<<<dim3(256), dim3(256), 0, stream>>>(w, wqf);
    // 32768 rows / 64 = 512 blocks (2 per CU), 8 waves each
    tern_gemm_kernel<<<dim3(512), dim3(512), 0, stream>>>(x, wqf, out);
}

// Round 4
// 358.850 us; speedup vs baseline: 1.2020x; 1.2020x over previous
//
#include <hip/hip_runtime.h>

#define THRESH 0.05f

typedef __attribute__((ext_vector_type(4)))  int   int32x4;
typedef __attribute__((ext_vector_type(16))) int   int32x16;
typedef __attribute__((ext_vector_type(4)))  float floatx4;

// ---------------------------------------------------------------------------
// Kernel 1: quantize weight [1024,1024] fp32 -> int8 {-1,0,+1} in FRAGMENT
// ORDER for the mfma_i32_32x32x32_i8 B-operand:
//   1 KB block per (nb,k):  wqf[((nb*32 + k)*64 + lane)*16 + byte]
//   lane l supplies w[col = nb*32 + (l&31)][k*32 + (l>>5)*16 .. +16)
// (unchanged -- verified absmax 0 in rounds 0/1/3.)
// ---------------------------------------------------------------------------
__global__ __launch_bounds__(256) void quant_w_kernel(const float* __restrict__ w,
                                                      signed char* __restrict__ wqf) {
    int c = blockIdx.x * 256 + threadIdx.x;   // 16-byte chunk id, 0..65535
    int l  = c & 63;
    int k  = (c >> 6) & 31;
    int nb = c >> 11;
    int col   = nb * 32 + (l & 31);
    int kbase = k * 32 + (l >> 5) * 16;
    const float* src = w + col * 1024 + kbase;
    signed char q[16];
    #pragma unroll
    for (int j = 0; j < 4; ++j) {
        float4 f = *(const float4*)(src + j * 4);
        q[j * 4 + 0] = (signed char)((f.x >= THRESH) - (f.x <= -THRESH));
        q[j * 4 + 1] = (signed char)((f.y >= THRESH) - (f.y <= -THRESH));
        q[j * 4 + 2] = (signed char)((f.z >= THRESH) - (f.z <= -THRESH));
        q[j * 4 + 3] = (signed char)((f.w >= THRESH) - (f.w <= -THRESH));
    }
    *(int32x4*)(wqf + (size_t)c * 16) = *(const int32x4*)q;
}

// ---------------------------------------------------------------------------
// Kernel 2: 64-row slab ternary GEMM, 32x32x32 i8 MFMA.
// Block = 512 threads (8 waves), 64 KB LDS, grid 512 -> 2 blocks/CU,
// 16 waves/CU.
// vs round 3 (287 us, REGRESSED): round 3 spilled -- 4 acc tiles (64 AGPR)
// + 32 rolling-B VGPR hit the 128-reg cap of __launch_bounds__(512,4);
// FETCH/WRITE both inflated ~250 MB (scratch round trips). Fix: wave owns
// ONE 32-col tile -> 2 acc (32 AGPR) + 8-deep rolling B (32 VGPR) ~= 92
// regs total, the footprint that compiled clean in round 1.
// Kept from round 3 (all verified correct, conflicts 2.1M -> 0.26M):
//  * 64-row slab: wqf L2 traffic 1 GB -> 512 MB vs round 1.
//  * fragment-order LDS, lane-XOR swizzle: conflict-free ds_read_b128 and
//    ds_write_b128. Block (k,ri) at (k*2+ri)*1024; slot = lane ^ (k&7).
//  * rolling B prefetch, no sched_barrier: no serialized L2 round trips.
// ---------------------------------------------------------------------------
__global__ __launch_bounds__(512, 4) void tern_gemm_kernel(const float* __restrict__ x,
                                                           const signed char* __restrict__ wqf,
                                                           float* __restrict__ out) {
    __shared__ __attribute__((aligned(16))) signed char a_lds[64 * 1024];
    const int tid = threadIdx.x;
    const long rowbase = (long)blockIdx.x * 64;

    // ---- Phase 1: stage + quantize x slab (64 rows x 1024 K) into
    //      fragment-order LDS. chunk c: row = c>>6, cir = c&63;
    //      k = cir>>1, ri = row>>5 ->
    //      addr = (k*2+ri)*1024 + (((cir&1)*32 + (row&31)) ^ (k&7))*16
    #pragma unroll
    for (int i = 0; i < 8; ++i) {
        int c   = tid + i * 512;   // chunk id 0..4095
        int row = c >> 6;          // 64 chunks per row
        int cir = c & 63;          // chunk-in-row
        const floatx4* src = (const floatx4*)(x + (rowbase + row) * 1024 + cir * 16);
        signed char q[16];
        #pragma unroll
        for (int j = 0; j < 4; ++j) {
            floatx4 f = __builtin_nontemporal_load(src + j);
            #pragma unroll
            for (int e = 0; e < 4; ++e)
                q[j * 4 + e] = (signed char)((f[e] >= THRESH) - (f[e] <= -THRESH));
        }
        int k    = cir >> 1;
        int blk  = k * 2 + (row >> 5);
        int slot = ((cir & 1) * 32 + (row & 31)) ^ (k & 7);
        *(int32x4*)(a_lds + blk * 1024 + slot * 16) = *(const int32x4*)q;
    }
    __syncthreads();

    // ---- Phase 2: compute. Wave owns ONE 32-col tile per ot (4 ot). ----
    const int wave = tid >> 6;    // 0..7
    const int lane = tid & 63;
    const int l31  = lane & 31;
    const int hi   = lane >> 5;

    for (int ot = 0; ot < 4; ++ot) {
        const int nb = ot * 8 + wave;        // this wave's 32-col tile
        const signed char* bp = wqf + (size_t)nb * 32768 + lane * 16;

        int32x16 acc0 = {0,0,0,0,0,0,0,0,0,0,0,0,0,0,0,0};  // rows  0..31
        int32x16 acc1 = acc0;                                 // rows 32..63

        // 8-deep rolling B prefetch (static indices only; rule #20)
        int32x4 b[8];
        #pragma unroll
        for (int j = 0; j < 8; ++j)
            b[j] = *(const int32x4*)(bp + (size_t)j * 1024);

        for (int kk = 0; kk < 24; kk += 8) {
            #pragma unroll
            for (int j = 0; j < 8; ++j) {
                const int k  = kk + j;
                const int sl = (lane ^ (k & 7)) * 16;
                int32x4 af0 = *(const int32x4*)(a_lds + (k * 2 + 0) * 1024 + sl);
                int32x4 af1 = *(const int32x4*)(a_lds + (k * 2 + 1) * 1024 + sl);
                acc0 = __builtin_amdgcn_mfma_i32_32x32x32_i8(af0, b[j], acc0, 0, 0, 0);
                acc1 = __builtin_amdgcn_mfma_i32_32x32x32_i8(af1, b[j], acc1, 0, 0, 0);
                // refill this slot with k+8 (compiler renames; loads float up)
                b[j] = *(const int32x4*)(bp + (size_t)(k + 8) * 1024);
            }
        }
        // tail k = 24..31, no prefetch
        #pragma unroll
        for (int j = 0; j < 8; ++j) {
            const int k  = 24 + j;
            const int sl = (lane ^ (k & 7)) * 16;
            int32x4 af0 = *(const int32x4*)(a_lds + (k * 2 + 0) * 1024 + sl);
            int32x4 af1 = *(const int32x4*)(a_lds + (k * 2 + 1) * 1024 + sl);
            acc0 = __builtin_amdgcn_mfma_i32_32x32x32_i8(af0, b[j], acc0, 0, 0, 0);
            acc1 = __builtin_amdgcn_mfma_i32_32x32x32_i8(af1, b[j], acc1, 0, 0, 0);
        }

        // ---- epilogue: scalar nt stores; per instr 64 lanes cover two
        //      contiguous 128 B row segments (rows rit, rit+4) ----
        const int cb = nb * 32 + l31;
        #pragma unroll
        for (int r = 0; r < 16; ++r) {
            const int rit = (r & 3) + 8 * (r >> 2) + 4 * hi;
            float* o0 = out + (rowbase + rit) * 1024 + cb;        // rows  0..31
            float* o1 = o0 + 32L * 1024;                          // rows 32..63
            __builtin_nontemporal_store((float)acc0[r], o0);
            __builtin_nontemporal_store((float)acc1[r], o1);
        }
    }
}

extern "C" void kernel_launch(void* const* d_in, const int* in_sizes, int n_in,
                              void* d_out, int out_size, void* d_ws, size_t ws_size,
                              hipStream_t stream) {
    const float* x = (const float*)d_in[0];      // [32768, 1024] fp32
    const float* w = (const float*)d_in[1];      // [1024, 1024] fp32
    float* out = (float*)d_out;                  // [32768, 1024] fp32
    signed char* wqf = (signed char*)d_ws;       // 1 MB int8 scratch (fragment order)

    quant_w_kernel<<<dim3(256), dim3(256), 0, stream>>>(w, wqf);
    // 32768 rows / 64 = 512 blocks (2 per CU), 8 waves each
    tern_gemm_kernel<<<dim3(512), dim3(512), 0, stream>>>(x, wqf, out);
}

// Round 5
// 265.507 us; speedup vs baseline: 1.6246x; 1.3516x over previous
//
#include <hip/hip_runtime.h>

#define THRESH 0.05f

typedef __attribute__((ext_vector_type(4)))  int   int32x4;
typedef __attribute__((ext_vector_type(16))) int   int32x16;
typedef __attribute__((ext_vector_type(4)))  float floatx4;

// ---------------------------------------------------------------------------
// Kernel 1: quantize weight [1024,1024] fp32 -> int8 {-1,0,+1} in FRAGMENT
// ORDER for the mfma_i32_32x32x32_i8 B-operand:
//   1 KB block per (nb,k):  wqf[((nb*32 + k)*64 + lane)*16 + byte]
//   lane l supplies w[col = nb*32 + (l&31)][k*32 + (l>>5)*16 .. +16)
// (unchanged -- verified absmax 0 in rounds 0/1/3/4.)
// ---------------------------------------------------------------------------
__global__ __launch_bounds__(256) void quant_w_kernel(const float* __restrict__ w,
                                                      signed char* __restrict__ wqf) {
    int c = blockIdx.x * 256 + threadIdx.x;   // 16-byte chunk id, 0..65535
    int l  = c & 63;
    int k  = (c >> 6) & 31;
    int nb = c >> 11;
    int col   = nb * 32 + (l & 31);
    int kbase = k * 32 + (l >> 5) * 16;
    const float* src = w + col * 1024 + kbase;
    signed char q[16];
    #pragma unroll
    for (int j = 0; j < 4; ++j) {
        float4 f = *(const float4*)(src + j * 4);
        q[j * 4 + 0] = (signed char)((f.x >= THRESH) - (f.x <= -THRESH));
        q[j * 4 + 1] = (signed char)((f.y >= THRESH) - (f.y <= -THRESH));
        q[j * 4 + 2] = (signed char)((f.z >= THRESH) - (f.z <= -THRESH));
        q[j * 4 + 3] = (signed char)((f.w >= THRESH) - (f.w <= -THRESH));
    }
    *(int32x4*)(wqf + (size_t)c * 16) = *(const int32x4*)q;
}

// ---------------------------------------------------------------------------
// Kernel 2: 64-row slab ternary GEMM, 32x32x32 i8 MFMA.
// Block = 512 threads (8 waves), 64 KB LDS, grid 512 -> 2 blocks/CU,
// 16 waves/CU.
// vs round 4 (208 us, REGRESSED): the 8-deep ROLLING refill doubled B's
// live ranges (old b[j] awaited by MFMA while new b[j] in flight -> ~64
// regs) -> silent spill (FETCH 471 MB / WRITE 313 MB; rocprof VGPR_Count
// does NOT expose spill, cf. round 3). Fix: revert B loads to round 1's
// PROVEN shape -- single-buffered burst-8 + sched_barrier(0), clean kill
// points, 60-VGPR class, zero traffic inflation at 105 us.
// Kept (verified correct, conflicts 2.1M -> 0.26M, absmax 0):
//  * 64-row slab: wqf L2 traffic 1 GB -> 512 MB vs the 32-row slab.
//  * one 32-col tile per wave: each b register feeds TWO MFMAs (rows 0-31
//    and 32-63) -> 2x MFMA work per L2 burst window; 4 waves/SIMD x
//    16 MFMA x 8 cyc = 512 cyc covers the ~250 cyc L2 latency.
//  * fragment-order LDS, lane-XOR swizzle: conflict-free ds_read_b128.
//    Block (k,ri) at (k*2+ri)*1024; slot = lane ^ (k&7).
// ---------------------------------------------------------------------------
__global__ __launch_bounds__(512, 4) void tern_gemm_kernel(const float* __restrict__ x,
                                                           const signed char* __restrict__ wqf,
                                                           float* __restrict__ out) {
    __shared__ __attribute__((aligned(16))) signed char a_lds[64 * 1024];
    const int tid = threadIdx.x;
    const long rowbase = (long)blockIdx.x * 64;

    // ---- Phase 1: stage + quantize x slab (64 rows x 1024 K) into
    //      fragment-order LDS. chunk c: row = c>>6, cir = c&63;
    //      k = cir>>1, ri = row>>5 ->
    //      addr = (k*2+ri)*1024 + (((cir&1)*32 + (row&31)) ^ (k&7))*16
    #pragma unroll
    for (int i = 0; i < 8; ++i) {
        int c   = tid + i * 512;   // chunk id 0..4095
        int row = c >> 6;          // 64 chunks per row
        int cir = c & 63;          // chunk-in-row
        const floatx4* src = (const floatx4*)(x + (rowbase + row) * 1024 + cir * 16);
        signed char q[16];
        #pragma unroll
        for (int j = 0; j < 4; ++j) {
            floatx4 f = __builtin_nontemporal_load(src + j);
            #pragma unroll
            for (int e = 0; e < 4; ++e)
                q[j * 4 + e] = (signed char)((f[e] >= THRESH) - (f[e] <= -THRESH));
        }
        int k    = cir >> 1;
        int blk  = k * 2 + (row >> 5);
        int slot = ((cir & 1) * 32 + (row & 31)) ^ (k & 7);
        *(int32x4*)(a_lds + blk * 1024 + slot * 16) = *(const int32x4*)q;
    }
    __syncthreads();

    // ---- Phase 2: compute. Wave owns ONE 32-col tile per ot (4 ot). ----
    const int wave = tid >> 6;    // 0..7
    const int lane = tid & 63;
    const int l31  = lane & 31;
    const int hi   = lane >> 5;

    for (int ot = 0; ot < 4; ++ot) {
        const int nb = ot * 8 + wave;        // this wave's 32-col tile
        const signed char* bp = wqf + (size_t)nb * 32768 + lane * 16;

        int32x16 acc0 = {0,0,0,0,0,0,0,0,0,0,0,0,0,0,0,0};  // rows  0..31
        int32x16 acc1 = acc0;                                 // rows 32..63

        // 4 bursts of 8 K-steps. Single-buffered b[8] (32 VGPR), fenced by
        // sched_barrier(0): loads of burst ks+1 may sink into burst ks's
        // MFMA region only as b registers die -> bounded pressure, no spill.
        #pragma unroll
        for (int ks = 0; ks < 4; ++ks) {
            int32x4 b[8];
            #pragma unroll
            for (int j = 0; j < 8; ++j)
                b[j] = *(const int32x4*)(bp + (size_t)(ks * 8 + j) * 1024);
            __builtin_amdgcn_sched_barrier(0);
            #pragma unroll
            for (int j = 0; j < 8; ++j) {
                const int k  = ks * 8 + j;
                const int sl = (lane ^ (k & 7)) * 16;
                int32x4 af0 = *(const int32x4*)(a_lds + (k * 2 + 0) * 1024 + sl);
                int32x4 af1 = *(const int32x4*)(a_lds + (k * 2 + 1) * 1024 + sl);
                acc0 = __builtin_amdgcn_mfma_i32_32x32x32_i8(af0, b[j], acc0, 0, 0, 0);
                acc1 = __builtin_amdgcn_mfma_i32_32x32x32_i8(af1, b[j], acc1, 0, 0, 0);
            }
        }

        // ---- epilogue: scalar nt stores; per instr 64 lanes cover two
        //      contiguous 128 B row segments (rows rit, rit+4) ----
        const int cb = nb * 32 + l31;
        #pragma unroll
        for (int r = 0; r < 16; ++r) {
            const int rit = (r & 3) + 8 * (r >> 2) + 4 * hi;
            float* o0 = out + (rowbase + rit) * 1024 + cb;        // rows  0..31
            float* o1 = o0 + 32L * 1024;                          // rows 32..63
            __builtin_nontemporal_store((float)acc0[r], o0);
            __builtin_nontemporal_store((float)acc1[r], o1);
        }
    }
}

extern "C" void kernel_launch(void* const* d_in, const int* in_sizes, int n_in,
                              void* d_out, int out_size, void* d_ws, size_t ws_size,
                              hipStream_t stream) {
    const float* x = (const float*)d_in[0];      // [32768, 1024] fp32
    const float* w = (const float*)d_in[1];      // [1024, 1024] fp32
    float* out = (float*)d_out;                  // [32768, 1024] fp32
    signed char* wqf = (signed char*)d_ws;       // 1 MB int8 scratch (fragment order)

    quant_w_kernel<<<dim3(256), dim3(256), 0, stream>>>(w, wqf);
    // 32768 rows / 64 = 512 blocks (2 per CU), 8 waves each
    tern_gemm_kernel<<<dim3(512), dim3(512), 0, stream>>>(x, wqf, out);
}